// Round 4
// baseline (44.431 us; speedup 1.0000x reference)
//
#include <hip/hip_runtime.h>

// BinancePerpStructuralLoss as a streaming stencil (no gather, no LDS staging).
// Per 20-col group: pairs (g,g+1) with d = x[g+1]-x[g]:
//   g<=8 -> +d (bid mono), 10<=g<=18 -> -d (ask mono), g==9,19 -> unused.
//   spread: relu(x[0]-x[10]) per group.
// out = (1/128) * sum over all B*T rows. Single kernel, per-block atomicAdd.

#define FEAT 240
#define F4_PER_ROW 60
#define NTHREADS 256
#define WAVES_PER_BLOCK 4
#define ROWS_PER_WAVE 16
#define ROWS_PER_BLOCK (WAVES_PER_BLOCK * ROWS_PER_WAVE)   // 64
#define BATCH_INV (1.0f / 128.0f)

__device__ __forceinline__ float pair_sign(int g, bool act) {
    if (!act) return 0.0f;
    if (g <= 8) return 1.0f;                 // bid monotonicity
    if (g >= 10 && g <= 18) return -1.0f;    // ask monotonicity
    return 0.0f;                             // g==9, g==19: no constraint
}

__device__ __forceinline__ float row_terms(float4 v, float nx, float zz,
                                           float s0, float s1, float s2, float s3,
                                           float ssp)
{
    return fmaxf(s0 * (v.y - v.x), 0.f) + fmaxf(s1 * (v.z - v.y), 0.f)
         + fmaxf(s2 * (v.w - v.z), 0.f) + fmaxf(s3 * (nx - v.w), 0.f)
         + fmaxf(ssp * (v.x - zz), 0.f);
}

__global__ __launch_bounds__(NTHREADS)
void bpsl_main(const float* __restrict__ pred, int n_rows, float* __restrict__ out)
{
    const int tid  = threadIdx.x;
    const int lane = tid & 63;
    const int widx = tid >> 6;
    const int gw   = blockIdx.x * WAVES_PER_BLOCK + widx;
    const int row0 = gw * ROWS_PER_WAVE;

    const bool act = lane < F4_PER_ROW;
    const int  lc  = act ? lane : (F4_PER_ROW - 1);   // clamped: loads always in-bounds
    const int  g0  = (lc * 4) % 20;                    // {0,4,8,12,16}

    const float s0  = pair_sign(g0 + 0, act);
    const float s1  = pair_sign(g0 + 1, act);
    const float s2  = pair_sign(g0 + 2, act);
    const float s3  = pair_sign(g0 + 3, act);
    const float ssp = (act && g0 == 0) ? 1.0f : 0.0f;  // spread lanes hold x[base+0]

    float acc = 0.0f;

    if (row0 < n_rows) {
        const float4* __restrict__ p =
            reinterpret_cast<const float4*>(pred) + (size_t)row0 * F4_PER_ROW + lc;
        const int rows = min(ROWS_PER_WAVE, n_rows - row0);

        int r = 0;
        #pragma unroll 1
        for (; r + 8 <= rows; r += 8) {
            // 8 independent loads in flight (contiguous rows -> linear stream)
            float4 v0 = p[0 * F4_PER_ROW];
            float4 v1 = p[1 * F4_PER_ROW];
            float4 v2 = p[2 * F4_PER_ROW];
            float4 v3 = p[3 * F4_PER_ROW];
            float4 v4 = p[4 * F4_PER_ROW];
            float4 v5 = p[5 * F4_PER_ROW];
            float4 v6 = p[6 * F4_PER_ROW];
            float4 v7 = p[7 * F4_PER_ROW];
            p += 8 * F4_PER_ROW;

            float nx0 = __shfl_down(v0.x, 1, 64), z0 = __shfl_down(v0.z, 2, 64);
            float nx1 = __shfl_down(v1.x, 1, 64), z1 = __shfl_down(v1.z, 2, 64);
            float nx2 = __shfl_down(v2.x, 1, 64), z2 = __shfl_down(v2.z, 2, 64);
            float nx3 = __shfl_down(v3.x, 1, 64), z3 = __shfl_down(v3.z, 2, 64);
            float nx4 = __shfl_down(v4.x, 1, 64), z4 = __shfl_down(v4.z, 2, 64);
            float nx5 = __shfl_down(v5.x, 1, 64), z5 = __shfl_down(v5.z, 2, 64);
            float nx6 = __shfl_down(v6.x, 1, 64), z6 = __shfl_down(v6.z, 2, 64);
            float nx7 = __shfl_down(v7.x, 1, 64), z7 = __shfl_down(v7.z, 2, 64);

            acc += row_terms(v0, nx0, z0, s0, s1, s2, s3, ssp);
            acc += row_terms(v1, nx1, z1, s0, s1, s2, s3, ssp);
            acc += row_terms(v2, nx2, z2, s0, s1, s2, s3, ssp);
            acc += row_terms(v3, nx3, z3, s0, s1, s2, s3, ssp);
            acc += row_terms(v4, nx4, z4, s0, s1, s2, s3, ssp);
            acc += row_terms(v5, nx5, z5, s0, s1, s2, s3, ssp);
            acc += row_terms(v6, nx6, z6, s0, s1, s2, s3, ssp);
            acc += row_terms(v7, nx7, z7, s0, s1, s2, s3, ssp);
        }
        #pragma unroll 1
        for (; r < rows; ++r) {            // tail (unused at 131072 rows)
            float4 v = p[0];
            p += F4_PER_ROW;
            float nx = __shfl_down(v.x, 1, 64), zz = __shfl_down(v.z, 2, 64);
            acc += row_terms(v, nx, zz, s0, s1, s2, s3, ssp);
        }
    }

    // wave reduce -> block reduce -> one pre-scaled atomic per block
    #pragma unroll
    for (int off = 32; off > 0; off >>= 1)
        acc += __shfl_down(acc, off, 64);

    __shared__ float wsum[WAVES_PER_BLOCK];
    if ((tid & 63) == 0) wsum[widx] = acc;
    __syncthreads();
    if (tid == 0) {
        float bs = wsum[0];
        #pragma unroll
        for (int w = 1; w < WAVES_PER_BLOCK; ++w) bs += wsum[w];
        atomicAdd(out, bs * BATCH_INV);
    }
}

extern "C" void kernel_launch(void* const* d_in, const int* in_sizes, int n_in,
                              void* d_out, int out_size, void* d_ws, size_t ws_size,
                              hipStream_t stream)
{
    const float* pred = (const float*)d_in[0];
    float*       out  = (float*)d_out;

    const int n_rows = in_sizes[0] / FEAT;                              // 131072
    const int grid   = (n_rows + ROWS_PER_BLOCK - 1) / ROWS_PER_BLOCK;  // 2048

    // atomic accumulation needs a fresh zero every call (harness doesn't re-poison)
    hipMemsetAsync(out, 0, sizeof(float), stream);
    bpsl_main<<<grid, NTHREADS, 0, stream>>>(pred, n_rows, out);
}

// Round 5
// 26.544 us; speedup vs baseline: 1.6739x; 1.6739x over previous
//
#include <hip/hip_runtime.h>

// BinancePerpStructuralLoss as a streaming stencil (no gather, no LDS staging).
// Per 20-col group: pairs (g,g+1) with d = x[g+1]-x[g]:
//   g<=8 -> +d (bid mono), 10<=g<=18 -> -d (ask mono), g==9,19 -> unused.
//   spread: relu(x[0]-x[10]) per group.
// out = (1/128) * sum over all B*T rows.
// Two-kernel reduction: per-block partials -> d_ws, tiny finisher. No atomics.

#define FEAT 240
#define F4_PER_ROW 60
#define NTHREADS 256
#define WAVES_PER_BLOCK 4
#define ROWS_PER_WAVE 32
#define ROWS_PER_BLOCK (WAVES_PER_BLOCK * ROWS_PER_WAVE)   // 128
#define BATCH_INV (1.0f / 128.0f)

__device__ __forceinline__ float pair_sign(int g, bool act) {
    if (!act) return 0.0f;
    if (g <= 8) return 1.0f;                 // bid monotonicity
    if (g >= 10 && g <= 18) return -1.0f;    // ask monotonicity
    return 0.0f;                             // g==9, g==19: no constraint
}

__device__ __forceinline__ float row_terms(float4 v, float nx, float zz,
                                           float s0, float s1, float s2, float s3,
                                           float ssp)
{
    return fmaxf(s0 * (v.y - v.x), 0.f) + fmaxf(s1 * (v.z - v.y), 0.f)
         + fmaxf(s2 * (v.w - v.z), 0.f) + fmaxf(s3 * (nx - v.w), 0.f)
         + fmaxf(ssp * (v.x - zz), 0.f);
}

template <bool ATOMIC>
__global__ __launch_bounds__(NTHREADS)
void bpsl_main(const float* __restrict__ pred, int n_rows, float* __restrict__ dst)
{
    const int tid  = threadIdx.x;
    const int lane = tid & 63;
    const int widx = tid >> 6;
    const int gw   = blockIdx.x * WAVES_PER_BLOCK + widx;
    const int row0 = gw * ROWS_PER_WAVE;

    const bool act = lane < F4_PER_ROW;
    const int  lc  = act ? lane : (F4_PER_ROW - 1);   // clamped: loads always in-bounds
    const int  g0  = (lc * 4) % 20;                    // {0,4,8,12,16}

    const float s0  = pair_sign(g0 + 0, act);
    const float s1  = pair_sign(g0 + 1, act);
    const float s2  = pair_sign(g0 + 2, act);
    const float s3  = pair_sign(g0 + 3, act);
    const float ssp = (act && g0 == 0) ? 1.0f : 0.0f;  // spread lanes hold x[base+0]

    float acc = 0.0f;

    if (row0 < n_rows) {
        const float4* __restrict__ p =
            reinterpret_cast<const float4*>(pred) + (size_t)row0 * F4_PER_ROW + lc;
        const int rows = min(ROWS_PER_WAVE, n_rows - row0);

        int r = 0;
        #pragma unroll 1
        for (; r + 4 <= rows; r += 4) {
            // 4 independent loads in flight (contiguous rows -> linear stream)
            float4 v0 = p[0 * F4_PER_ROW];
            float4 v1 = p[1 * F4_PER_ROW];
            float4 v2 = p[2 * F4_PER_ROW];
            float4 v3 = p[3 * F4_PER_ROW];
            p += 4 * F4_PER_ROW;

            float nx0 = __shfl_down(v0.x, 1, 64), z0 = __shfl_down(v0.z, 2, 64);
            float nx1 = __shfl_down(v1.x, 1, 64), z1 = __shfl_down(v1.z, 2, 64);
            float nx2 = __shfl_down(v2.x, 1, 64), z2 = __shfl_down(v2.z, 2, 64);
            float nx3 = __shfl_down(v3.x, 1, 64), z3 = __shfl_down(v3.z, 2, 64);

            acc += row_terms(v0, nx0, z0, s0, s1, s2, s3, ssp);
            acc += row_terms(v1, nx1, z1, s0, s1, s2, s3, ssp);
            acc += row_terms(v2, nx2, z2, s0, s1, s2, s3, ssp);
            acc += row_terms(v3, nx3, z3, s0, s1, s2, s3, ssp);
        }
        #pragma unroll 1
        for (; r < rows; ++r) {            // tail (unused at 131072 rows)
            float4 v = p[0];
            p += F4_PER_ROW;
            float nx = __shfl_down(v.x, 1, 64), zz = __shfl_down(v.z, 2, 64);
            acc += row_terms(v, nx, zz, s0, s1, s2, s3, ssp);
        }
    }

    // wave reduce -> block reduce -> one write (or atomic fallback) per block
    #pragma unroll
    for (int off = 32; off > 0; off >>= 1)
        acc += __shfl_down(acc, off, 64);

    __shared__ float wsum[WAVES_PER_BLOCK];
    if ((tid & 63) == 0) wsum[widx] = acc;
    __syncthreads();
    if (tid == 0) {
        float bs = wsum[0];
        #pragma unroll
        for (int w = 1; w < WAVES_PER_BLOCK; ++w) bs += wsum[w];
        if (ATOMIC) atomicAdd(dst, bs * BATCH_INV);
        else        dst[blockIdx.x] = bs;
    }
}

__global__ __launch_bounds__(NTHREADS)
void bpsl_finish(const float* __restrict__ ws, int n, float* __restrict__ out)
{
    float a = 0.0f;
    for (int i = threadIdx.x; i < n; i += NTHREADS) a += ws[i];
    #pragma unroll
    for (int off = 32; off > 0; off >>= 1)
        a += __shfl_down(a, off, 64);
    __shared__ float wsum[NTHREADS / 64];
    if ((threadIdx.x & 63) == 0) wsum[threadIdx.x >> 6] = a;
    __syncthreads();
    if (threadIdx.x == 0) {
        float t = wsum[0] + wsum[1] + wsum[2] + wsum[3];
        out[0] = t * BATCH_INV;
    }
}

extern "C" void kernel_launch(void* const* d_in, const int* in_sizes, int n_in,
                              void* d_out, int out_size, void* d_ws, size_t ws_size,
                              hipStream_t stream)
{
    const float* pred = (const float*)d_in[0];
    float*       out  = (float*)d_out;
    float*       ws   = (float*)d_ws;

    const int n_rows = in_sizes[0] / FEAT;                              // 131072
    const int grid   = (n_rows + ROWS_PER_BLOCK - 1) / ROWS_PER_BLOCK;  // 1024

    if (ws_size >= (size_t)grid * sizeof(float)) {
        bpsl_main<false><<<grid, NTHREADS, 0, stream>>>(pred, n_rows, ws);
        bpsl_finish<<<1, NTHREADS, 0, stream>>>(ws, grid, out);
    } else {
        hipMemsetAsync(out, 0, sizeof(float), stream);
        bpsl_main<true><<<grid, NTHREADS, 0, stream>>>(pred, n_rows, out);
    }
}

// Round 7
// 25.165 us; speedup vs baseline: 1.7656x; 1.0548x over previous
//
#include <hip/hip_runtime.h>

// BinancePerpStructuralLoss as a streaming stencil (no gather, no LDS staging).
// Per 20-col group: pairs (g,g+1) with d = x[g+1]-x[g]:
//   g<=8 -> +d (bid mono), 10<=g<=18 -> -d (ask mono), g==9,19 -> unused.
//   spread: relu(x[0]-x[10]) per group.
// out = (1/128) * sum over all B*T rows.
// Two-kernel reduction: per-block partials -> d_ws, single-wave finisher.
// No same-address atomic storms (R3 lesson: ~9ns/atomic serialized tail).

#define FEAT 240
#define F4_PER_ROW 60
#define NTHREADS 256
#define WAVES_PER_BLOCK 4
#define ROWS_PER_WAVE 32
#define ROWS_PER_BLOCK (WAVES_PER_BLOCK * ROWS_PER_WAVE)   // 128
#define BATCH_INV (1.0f / 128.0f)

typedef float vfloat4 __attribute__((ext_vector_type(4)));  // native vec for nt builtin

__device__ __forceinline__ float pair_sign(int g, bool act) {
    if (!act) return 0.0f;
    if (g <= 8) return 1.0f;                 // bid monotonicity
    if (g >= 10 && g <= 18) return -1.0f;    // ask monotonicity
    return 0.0f;                             // g==9, g==19: no constraint
}

__device__ __forceinline__ float row_terms(vfloat4 v, float nx, float zz,
                                           float s0, float s1, float s2, float s3,
                                           float ssp)
{
    return fmaxf(s0 * (v.y - v.x), 0.f) + fmaxf(s1 * (v.z - v.y), 0.f)
         + fmaxf(s2 * (v.w - v.z), 0.f) + fmaxf(s3 * (nx - v.w), 0.f)
         + fmaxf(ssp * (v.x - zz), 0.f);
}

__device__ __forceinline__ vfloat4 nt_load4(const float* p) {
    // read-once stream: hint early eviction in L2/MALL
    return __builtin_nontemporal_load(reinterpret_cast<const vfloat4*>(p));
}

template <bool ATOMIC>
__global__ __launch_bounds__(NTHREADS)
void bpsl_main(const float* __restrict__ pred, int n_rows, float* __restrict__ dst)
{
    const int tid  = threadIdx.x;
    const int lane = tid & 63;
    const int widx = tid >> 6;
    const int gw   = blockIdx.x * WAVES_PER_BLOCK + widx;
    const int row0 = gw * ROWS_PER_WAVE;

    const bool act = lane < F4_PER_ROW;
    const int  lc  = act ? lane : (F4_PER_ROW - 1);   // clamped: loads always in-bounds
    const int  g0  = (lc * 4) % 20;                    // {0,4,8,12,16}

    const float s0  = pair_sign(g0 + 0, act);
    const float s1  = pair_sign(g0 + 1, act);
    const float s2  = pair_sign(g0 + 2, act);
    const float s3  = pair_sign(g0 + 3, act);
    const float ssp = (act && g0 == 0) ? 1.0f : 0.0f;  // spread lanes hold x[base+0]

    float acc = 0.0f;

    if (row0 < n_rows) {
        const float* __restrict__ p =
            pred + ((size_t)row0 * F4_PER_ROW + lc) * 4;
        const int rows = min(ROWS_PER_WAVE, n_rows - row0);

        int r = 0;
        #pragma unroll 1
        for (; r + 4 <= rows; r += 4) {
            // 4 independent loads in flight (contiguous rows -> linear stream)
            vfloat4 v0 = nt_load4(p + 0 * FEAT);
            vfloat4 v1 = nt_load4(p + 1 * FEAT);
            vfloat4 v2 = nt_load4(p + 2 * FEAT);
            vfloat4 v3 = nt_load4(p + 3 * FEAT);
            p += 4 * FEAT;

            float nx0 = __shfl_down(v0.x, 1, 64), z0 = __shfl_down(v0.z, 2, 64);
            float nx1 = __shfl_down(v1.x, 1, 64), z1 = __shfl_down(v1.z, 2, 64);
            float nx2 = __shfl_down(v2.x, 1, 64), z2 = __shfl_down(v2.z, 2, 64);
            float nx3 = __shfl_down(v3.x, 1, 64), z3 = __shfl_down(v3.z, 2, 64);

            acc += row_terms(v0, nx0, z0, s0, s1, s2, s3, ssp);
            acc += row_terms(v1, nx1, z1, s0, s1, s2, s3, ssp);
            acc += row_terms(v2, nx2, z2, s0, s1, s2, s3, ssp);
            acc += row_terms(v3, nx3, z3, s0, s1, s2, s3, ssp);
        }
        #pragma unroll 1
        for (; r < rows; ++r) {            // tail (unused at 131072 rows)
            vfloat4 v = nt_load4(p);
            p += FEAT;
            float nx = __shfl_down(v.x, 1, 64), zz = __shfl_down(v.z, 2, 64);
            acc += row_terms(v, nx, zz, s0, s1, s2, s3, ssp);
        }
    }

    // wave reduce -> block reduce -> one write (or atomic fallback) per block
    #pragma unroll
    for (int off = 32; off > 0; off >>= 1)
        acc += __shfl_down(acc, off, 64);

    __shared__ float wsum[WAVES_PER_BLOCK];
    if ((tid & 63) == 0) wsum[widx] = acc;
    __syncthreads();
    if (tid == 0) {
        float bs = wsum[0];
        #pragma unroll
        for (int w = 1; w < WAVES_PER_BLOCK; ++w) bs += wsum[w];
        if (ATOMIC) atomicAdd(dst, bs * BATCH_INV);
        else        dst[blockIdx.x] = bs;
    }
}

// Single-wave finisher: n4 = grid/4 float4s; no LDS, no barrier.
__global__ __launch_bounds__(64)
void bpsl_finish(const float* __restrict__ ws, int n4, float* __restrict__ out)
{
    const int lane = threadIdx.x;
    const float4* w4 = reinterpret_cast<const float4*>(ws);
    float a = 0.0f;
    for (int i = lane; i < n4; i += 64) {
        float4 v = w4[i];
        a += (v.x + v.y) + (v.z + v.w);
    }
    #pragma unroll
    for (int off = 32; off > 0; off >>= 1)
        a += __shfl_down(a, off, 64);
    if (lane == 0) out[0] = a * BATCH_INV;
}

extern "C" void kernel_launch(void* const* d_in, const int* in_sizes, int n_in,
                              void* d_out, int out_size, void* d_ws, size_t ws_size,
                              hipStream_t stream)
{
    const float* pred = (const float*)d_in[0];
    float*       out  = (float*)d_out;
    float*       ws   = (float*)d_ws;

    const int n_rows = in_sizes[0] / FEAT;                              // 131072
    const int grid   = (n_rows + ROWS_PER_BLOCK - 1) / ROWS_PER_BLOCK;  // 1024

    if (ws_size >= (size_t)grid * sizeof(float) && (grid % 4) == 0) {
        bpsl_main<false><<<grid, NTHREADS, 0, stream>>>(pred, n_rows, ws);
        bpsl_finish<<<1, 64, 0, stream>>>(ws, grid / 4, out);
    } else {
        (void)hipMemsetAsync(out, 0, sizeof(float), stream);
        bpsl_main<true><<<grid, NTHREADS, 0, stream>>>(pred, n_rows, out);
    }
}